// Round 1
// baseline (411.376 us; speedup 1.0000x reference)
//
#include <hip/hip_runtime.h>

#define C_CH 128
#define N_EL 262144          // 512*512 per channel
#define NBINS 256
#define FB 4096              // fine histogram bins
#define BPC_MM 16            // blocks per channel, minmax
#define BPC_H 8              // blocks per channel, hist

// ---- order-preserving float <-> uint encoding for atomic min/max ----
__device__ __forceinline__ unsigned fenc(float f) {
  unsigned b = __float_as_uint(f);
  return b ^ ((unsigned)((int)b >> 31) | 0x80000000u);
}
__device__ __forceinline__ float fdec(unsigned u) {
  unsigned b = (u & 0x80000000u) ? (u ^ 0x80000000u) : ~u;
  return __uint_as_float(b);
}

// ws layout: umin[C] (u32) | umax[C] (u32) | sumx2[C] (f32) | fineCnt[C*FB] | fineSum[C*FB]

__global__ __launch_bounds__(256) void k_init(unsigned* umin, unsigned* umax, float* sumx2,
                                              float* fineCnt, float* fineSum, float* dout) {
  int i = blockIdx.x * blockDim.x + threadIdx.x;
  int st = gridDim.x * blockDim.x;
  for (int j = i; j < C_CH; j += st) { umin[j] = 0xFFFFFFFFu; umax[j] = 0u; sumx2[j] = 0.f; }
  for (int j = i; j < C_CH * FB; j += st) { fineCnt[j] = 0.f; fineSum[j] = 0.f; }
  for (int j = i; j < 1 + C_CH * NBINS; j += st) dout[j] = 0.f;  // loss + hist
}

__global__ __launch_bounds__(256) void k_minmax(const float* __restrict__ inp,
                                                const float* __restrict__ mask,
                                                unsigned* __restrict__ umin,
                                                unsigned* __restrict__ umax) {
  const int SEG = N_EL / BPC_MM;
  int c = blockIdx.x / BPC_MM;
  int seg = blockIdx.x % BPC_MM;
  const float4* in4 = (const float4*)(inp + (size_t)c * N_EL + (size_t)seg * SEG);
  const float4* mk4 = (const float4*)(mask + (size_t)seg * SEG);
  float mn = INFINITY, mx = -INFINITY;
  for (int i = threadIdx.x; i < SEG / 4; i += 256) {
    float4 a = in4[i], m = mk4[i];
    float x0 = a.x * m.x, x1 = a.y * m.y, x2 = a.z * m.z, x3 = a.w * m.w;
    mn = fminf(mn, fminf(fminf(x0, x1), fminf(x2, x3)));
    mx = fmaxf(mx, fmaxf(fmaxf(x0, x1), fmaxf(x2, x3)));
  }
  for (int o = 32; o > 0; o >>= 1) { mn = fminf(mn, __shfl_xor(mn, o)); mx = fmaxf(mx, __shfl_xor(mx, o)); }
  __shared__ float smn[4], smx[4];
  if ((threadIdx.x & 63) == 0) { smn[threadIdx.x >> 6] = mn; smx[threadIdx.x >> 6] = mx; }
  __syncthreads();
  if (threadIdx.x == 0) {
    mn = fminf(fminf(smn[0], smn[1]), fminf(smn[2], smn[3]));
    mx = fmaxf(fmaxf(smx[0], smx[1]), fmaxf(smx[2], smx[3]));
    atomicMin(&umin[c], fenc(mn));
    atomicMax(&umax[c], fenc(mx));
  }
}

__global__ __launch_bounds__(256) void k_hist(const float* __restrict__ inp,
                                              const float* __restrict__ mask,
                                              const unsigned* __restrict__ umin,
                                              const unsigned* __restrict__ umax,
                                              float* __restrict__ fineCnt,
                                              float* __restrict__ fineSum,
                                              float* __restrict__ sumx2,
                                              float* __restrict__ outHist) {
  __shared__ unsigned lh[NBINS];
  __shared__ unsigned lfc[FB];
  __shared__ float lfs[FB];
  const int SEG = N_EL / BPC_H;
  int c = blockIdx.x / BPC_H, seg = blockIdx.x % BPC_H;
  for (int i = threadIdx.x; i < FB; i += 256) { lfc[i] = 0u; lfs[i] = 0.f; }
  for (int i = threadIdx.x; i < NBINS; i += 256) lh[i] = 0u;
  __syncthreads();
  float mn = fdec(umin[c]), mx = fdec(umax[c]);
  float inv = 1.0f / fmaxf(mx - mn, 1e-8f);
  const float4* in4 = (const float4*)(inp + (size_t)c * N_EL + (size_t)seg * SEG);
  const float4* mk4 = (const float4*)(mask + (size_t)seg * SEG);
  float sx2 = 0.f;
  for (int i = threadIdx.x; i < SEG / 4; i += 256) {
    float4 a = in4[i], m = mk4[i];
    float xs[4] = {a.x * m.x, a.y * m.y, a.z * m.z, a.w * m.w};
#pragma unroll
    for (int k = 0; k < 4; ++k) {
      float x = xs[k];
      sx2 += x * x;
      float v = (x - mn) * inv;
      int b = (int)(v * 255.0f); b = min(max(b, 0), NBINS - 1);
      atomicAdd(&lh[b], 1u);
      int fb = (int)(v * (float)FB); fb = min(max(fb, 0), FB - 1);
      atomicAdd(&lfc[fb], 1u);
      atomicAdd(&lfs[fb], x);
    }
  }
  // block-reduce sum of squares
  for (int o = 32; o > 0; o >>= 1) sx2 += __shfl_xor(sx2, o);
  __shared__ float sw[4];
  if ((threadIdx.x & 63) == 0) sw[threadIdx.x >> 6] = sx2;
  __syncthreads();   // also orders all LDS atomics before flush
  if (threadIdx.x == 0) atomicAdd(&sumx2[c], sw[0] + sw[1] + sw[2] + sw[3]);
  for (int i = threadIdx.x; i < NBINS; i += 256)
    if (lh[i]) atomicAdd(&outHist[c * NBINS + i], (float)lh[i]);
  for (int i = threadIdx.x; i < FB; i += 256)
    if (lfc[i]) {
      atomicAdd(&fineCnt[c * FB + i], (float)lfc[i]);
      atomicAdd(&fineSum[c * FB + i], lfs[i]);
    }
}

__global__ __launch_bounds__(256) void k_fin(const float* __restrict__ th,
                                             const float* __restrict__ tmn_p,
                                             const float* __restrict__ tmx_p,
                                             const unsigned* __restrict__ umin,
                                             const unsigned* __restrict__ umax,
                                             const float* __restrict__ sumx2,
                                             const float* __restrict__ fineCnt,
                                             const float* __restrict__ fineSum,
                                             float* __restrict__ dout) {
  __shared__ float sCnt[FB], sSum[FB];
  __shared__ float totC[256], totS[256];
  __shared__ float sCdf[NBINS];
  __shared__ float sS1[NBINS];
  __shared__ int sK[NBINS];
  __shared__ float red[4];
  int c = blockIdx.x, tid = threadIdx.x;
  for (int i = tid; i < FB; i += 256) { sCnt[i] = fineCnt[c * FB + i]; sSum[i] = fineSum[c * FB + i]; }
  __syncthreads();
  // inclusive scan of counts & sums: 16-elem serial per thread, then thread-total scan
  {
    float a = 0.f, b = 0.f;
    int base = tid * (FB / 256);
    for (int k = 0; k < FB / 256; ++k) {
      a += sCnt[base + k]; sCnt[base + k] = a;
      b += sSum[base + k]; sSum[base + k] = b;
    }
    totC[tid] = a; totS[tid] = b;
  }
  __syncthreads();
  if (tid == 0) {
    float a = 0.f, b = 0.f;
    for (int i = 0; i < 256; ++i) { a += totC[i]; totC[i] = a; b += totS[i]; totS[i] = b; }
  }
  __syncthreads();
  {
    float offC = tid ? totC[tid - 1] : 0.f, offS = tid ? totS[tid - 1] : 0.f;
    int base = tid * (FB / 256);
    for (int k = 0; k < FB / 256; ++k) { sCnt[base + k] += offC; sSum[base + k] += offS; }
  }
  // replicate jnp: cdf = cumsum(hist); cdf = cdf/cdf[-1]*N  (f32)
  if (tid == 0) {
    float a = 0.f;
    for (int j = 0; j < NBINS; ++j) { a += th[c * NBINS + j]; sCdf[j] = a; }
  }
  __syncthreads();
  float total = sCdf[NBINS - 1];
  int j = tid;
  float cs = (sCdf[j] / total) * (float)N_EL;
  int kj = (int)floorf(cs);
  kj = min(max(kj, 0), N_EL);
  float fk = (float)kj;
  float totCnt = sCnt[FB - 1], totSum = sSum[FB - 1];
  float S1;
  if (kj <= 0) S1 = 0.f;
  else if (fk >= totCnt) S1 = totSum;
  else {
    int lo = 0, hi = FB - 1;
    while (lo < hi) { int mid = (lo + hi) >> 1; if (sCnt[mid] >= fk) hi = mid; else lo = mid + 1; }
    float cP = lo ? sCnt[lo - 1] : 0.f, sP = lo ? sSum[lo - 1] : 0.f;
    float cb = sCnt[lo] - cP, sb = sSum[lo] - sP;
    S1 = sP + (fk - cP) * (cb > 0.f ? sb / cb : 0.f);
  }
  sS1[j] = S1; sK[j] = kj;
  __syncthreads();
  int kP = j ? sK[j - 1] : 0;
  float S1P = j ? sS1[j - 1] : 0.f;
  // last bin absorbs everything up to N exactly (clip in searchsorted)
  float kjEff = (j == NBINS - 1) ? (float)N_EL : (float)kj;
  float S1Eff = (j == NBINS - 1) ? totSum : S1;
  float cj = kjEff - (float)kP;
  float dS1 = S1Eff - S1P;
  float tmn = tmn_p[c], tmx = tmx_p[c];
  float tj = ((float)j / 255.0f) * (tmx - tmn) + tmn;
  float part = cj * tj * tj - 2.0f * tj * dS1;
  for (int o = 32; o > 0; o >>= 1) part += __shfl_xor(part, o);
  if ((tid & 63) == 0) red[tid >> 6] = part;
  __syncthreads();
  if (tid == 0) {
    float Lc = red[0] + red[1] + red[2] + red[3] + sumx2[c];
    atomicAdd(&dout[0], Lc * (0.01f / ((float)C_CH * (float)N_EL)));
    dout[1 + C_CH * NBINS + c] = fdec(umin[c]);          // cur_min
    dout[1 + C_CH * NBINS + C_CH + c] = fdec(umax[c]);   // cur_max
  }
}

extern "C" void kernel_launch(void* const* d_in, const int* in_sizes, int n_in,
                              void* d_out, int out_size, void* d_ws, size_t ws_size,
                              hipStream_t stream) {
  const float* inp  = (const float*)d_in[0];
  const float* mask = (const float*)d_in[1];
  const float* th   = (const float*)d_in[2];
  const float* tmn  = (const float*)d_in[3];
  const float* tmx  = (const float*)d_in[4];
  float* out = (float*)d_out;

  unsigned* umin = (unsigned*)d_ws;
  unsigned* umax = umin + C_CH;
  float* sumx2   = (float*)(umax + C_CH);
  float* fineCnt = sumx2 + C_CH;
  float* fineSum = fineCnt + (size_t)C_CH * FB;

  hipLaunchKernelGGL(k_init, dim3(1024), dim3(256), 0, stream,
                     umin, umax, sumx2, fineCnt, fineSum, out);
  hipLaunchKernelGGL(k_minmax, dim3(C_CH * BPC_MM), dim3(256), 0, stream,
                     inp, mask, umin, umax);
  hipLaunchKernelGGL(k_hist, dim3(C_CH * BPC_H), dim3(256), 0, stream,
                     inp, mask, umin, umax, fineCnt, fineSum, sumx2, out + 1);
  hipLaunchKernelGGL(k_fin, dim3(C_CH), dim3(256), 0, stream,
                     th, tmn, tmx, umin, umax, sumx2, fineCnt, fineSum, out);
}

// Round 2
// 255.624 us; speedup vs baseline: 1.6093x; 1.6093x over previous
//
#include <hip/hip_runtime.h>

#define C_CH 128
#define N_EL 262144          // 512*512 per channel
#define NBINS 256
#define FB 4096              // fine array size; bins used: 0..4080 (4080 = 16*255)
#define FBINS 4080.0f
#define BPC_MM 16            // blocks per channel, minmax
#define BPC_H 8              // blocks per channel, hist
typedef unsigned long long u64;

// ---- order-preserving float <-> uint encoding for atomic min/max ----
__device__ __forceinline__ unsigned fenc(float f) {
  unsigned b = __float_as_uint(f);
  return b ^ ((unsigned)((int)b >> 31) | 0x80000000u);
}
__device__ __forceinline__ float fdec(unsigned u) {
  unsigned b = (u & 0x80000000u) ? (u ^ 0x80000000u) : ~u;
  return __uint_as_float(b);
}

// ws layout: umin[C] | umax[C] | sumx2[C] | fineCnt[C*FB] | fineFrac[C*FB]

__global__ __launch_bounds__(256) void k_init(unsigned* umin, unsigned* umax, float* sumx2,
                                              float* fineCnt, float* fineFrac, float* dout) {
  int i = blockIdx.x * blockDim.x + threadIdx.x;
  int st = gridDim.x * blockDim.x;
  for (int j = i; j < C_CH; j += st) { umin[j] = 0xFFFFFFFFu; umax[j] = 0u; sumx2[j] = 0.f; }
  for (int j = i; j < C_CH * FB; j += st) { fineCnt[j] = 0.f; fineFrac[j] = 0.f; }
  for (int j = i; j < 1 + C_CH * NBINS; j += st) dout[j] = 0.f;  // loss + hist
}

__global__ __launch_bounds__(256) void k_minmax(const float* __restrict__ inp,
                                                const float* __restrict__ mask,
                                                unsigned* __restrict__ umin,
                                                unsigned* __restrict__ umax) {
  const int SEG = N_EL / BPC_MM;      // 16384 elements, 4096 float4
  int c = blockIdx.x / BPC_MM;
  int seg = blockIdx.x % BPC_MM;
  const float4* in4 = (const float4*)(inp + (size_t)c * N_EL + (size_t)seg * SEG);
  const float4* mk4 = (const float4*)(mask + (size_t)seg * SEG);
  float mn = INFINITY, mx = -INFINITY;
  int tid = threadIdx.x;
#pragma unroll
  for (int i = 0; i < 4; ++i) {
    float4 a0 = in4[i * 1024 + 0 * 256 + tid];
    float4 a1 = in4[i * 1024 + 1 * 256 + tid];
    float4 a2 = in4[i * 1024 + 2 * 256 + tid];
    float4 a3 = in4[i * 1024 + 3 * 256 + tid];
    float4 m0 = mk4[i * 1024 + 0 * 256 + tid];
    float4 m1 = mk4[i * 1024 + 1 * 256 + tid];
    float4 m2 = mk4[i * 1024 + 2 * 256 + tid];
    float4 m3 = mk4[i * 1024 + 3 * 256 + tid];
    float4 av[4] = {a0, a1, a2, a3};
    float4 mv[4] = {m0, m1, m2, m3};
#pragma unroll
    for (int k = 0; k < 4; ++k) {
      float x0 = av[k].x * mv[k].x, x1 = av[k].y * mv[k].y;
      float x2 = av[k].z * mv[k].z, x3 = av[k].w * mv[k].w;
      mn = fminf(mn, fminf(fminf(x0, x1), fminf(x2, x3)));
      mx = fmaxf(mx, fmaxf(fmaxf(x0, x1), fmaxf(x2, x3)));
    }
  }
  for (int o = 32; o > 0; o >>= 1) { mn = fminf(mn, __shfl_xor(mn, o)); mx = fmaxf(mx, __shfl_xor(mx, o)); }
  __shared__ float smn[4], smx[4];
  if ((tid & 63) == 0) { smn[tid >> 6] = mn; smx[tid >> 6] = mx; }
  __syncthreads();
  if (tid == 0) {
    mn = fminf(fminf(smn[0], smn[1]), fminf(smn[2], smn[3]));
    mx = fmaxf(fmaxf(smx[0], smx[1]), fmaxf(smx[2], smx[3]));
    atomicMin(&umin[c], fenc(mn));
    atomicMax(&umax[c], fenc(mx));
  }
}

__global__ __launch_bounds__(512) void k_hist(const float* __restrict__ inp,
                                              const float* __restrict__ mask,
                                              const unsigned* __restrict__ umin,
                                              const unsigned* __restrict__ umax,
                                              float* __restrict__ fineCnt,
                                              float* __restrict__ fineFrac,
                                              float* __restrict__ sumx2,
                                              float* __restrict__ outHist) {
  __shared__ u64 lh[FB];              // 32 KB: (cnt<<46) | sum(frac * 2^28)
  const int SEG = N_EL / BPC_H;       // 32768 elements, 8192 float4
  int c = blockIdx.x / BPC_H, seg = blockIdx.x % BPC_H;
  int tid = threadIdx.x;
  for (int i = tid; i < FB; i += 512) lh[i] = 0ull;
  __syncthreads();
  float mn = fdec(umin[c]), mx = fdec(umax[c]);
  float inv = FBINS / fmaxf(mx - mn, 1e-8f);
  const float4* in4 = (const float4*)(inp + (size_t)c * N_EL + (size_t)seg * SEG);
  const float4* mk4 = (const float4*)(mask + (size_t)seg * SEG);
  float sx2 = 0.f;
#pragma unroll
  for (int i = 0; i < 8; ++i) {
    float4 a0 = in4[i * 1024 + tid];
    float4 a1 = in4[i * 1024 + 512 + tid];
    float4 m0 = mk4[i * 1024 + tid];
    float4 m1 = mk4[i * 1024 + 512 + tid];
    float xs[8] = {a0.x * m0.x, a0.y * m0.y, a0.z * m0.z, a0.w * m0.w,
                   a1.x * m1.x, a1.y * m1.y, a1.z * m1.z, a1.w * m1.w};
#pragma unroll
    for (int k = 0; k < 8; ++k) {
      float x = xs[k];
      sx2 += x * x;
      float vv = (x - mn) * inv;                 // position in fine-bin units
      vv = fminf(fmaxf(vv, 0.f), FBINS);         // [0, 4080]
      int fb = (int)vv;
      float frac = vv - (float)fb;               // [0,1)
      u64 pkt = (1ull << 46) | (u64)(frac * 268435456.0f);  // frac * 2^28
      atomicAdd(&lh[fb], pkt);
    }
  }
  // block-reduce sum of squares
  for (int o = 32; o > 0; o >>= 1) sx2 += __shfl_xor(sx2, o);
  __shared__ float sw[8];
  if ((tid & 63) == 0) sw[tid >> 6] = sx2;
  __syncthreads();   // also orders all LDS atomics before flush
  if (tid == 0) {
    float t = 0.f;
    for (int k = 0; k < 8; ++k) t += sw[k];
    atomicAdd(&sumx2[c], t);
  }
  // flush fine hist (cnt + frac-sum) to global
  for (int i = tid; i < FB; i += 512) {
    u64 pk = lh[i];
    if (pk) {
      atomicAdd(&fineCnt[(size_t)c * FB + i], (float)(unsigned)(pk >> 46));
      atomicAdd(&fineFrac[(size_t)c * FB + i], (float)(pk & ((1ull << 46) - 1)) * (1.0f / 268435456.0f));
    }
  }
  // coarse 256-bin hist derived: coarse b = fb >> 4 (4080 = 16*255; bins 4081..4095 are zero)
  if (tid < NBINS) {
    float cb = 0.f;
    for (int k = 0; k < 16; ++k) cb += (float)(unsigned)(lh[16 * tid + k] >> 46);
    if (cb != 0.f) atomicAdd(&outHist[(size_t)c * NBINS + tid], cb);
  }
}

__global__ __launch_bounds__(256) void k_fin(const float* __restrict__ th,
                                             const float* __restrict__ tmn_p,
                                             const float* __restrict__ tmx_p,
                                             const unsigned* __restrict__ umin,
                                             const unsigned* __restrict__ umax,
                                             const float* __restrict__ sumx2,
                                             const float* __restrict__ fineCnt,
                                             const float* __restrict__ fineFrac,
                                             float* __restrict__ dout) {
  __shared__ float sCnt[FB], sPos[FB];
  __shared__ float totC[256], totS[256];
  __shared__ float sCdf[NBINS];
  __shared__ float sS1[NBINS];
  __shared__ int sK[NBINS];
  __shared__ float red[4];
  int c = blockIdx.x, tid = threadIdx.x;
  float mn = fdec(umin[c]), mx = fdec(umax[c]);
  float w = fmaxf(mx - mn, 1e-8f) / FBINS;       // fine-bin width (inverse of k_hist's inv)
  for (int i = tid; i < FB; i += 256) {
    float cn = fineCnt[(size_t)c * FB + i];
    sCnt[i] = cn;
    sPos[i] = cn * (float)i + fineFrac[(size_t)c * FB + i];  // sum of (fb+frac) in bin
  }
  __syncthreads();
  // inclusive scan: 16-elem serial per thread, then thread-total scan
  {
    float a = 0.f, b = 0.f;
    int base = tid * (FB / 256);
    for (int k = 0; k < FB / 256; ++k) {
      a += sCnt[base + k]; sCnt[base + k] = a;
      b += sPos[base + k]; sPos[base + k] = b;
    }
    totC[tid] = a; totS[tid] = b;
  }
  __syncthreads();
  if (tid == 0) {
    float a = 0.f, b = 0.f;
    for (int i = 0; i < 256; ++i) { a += totC[i]; totC[i] = a; b += totS[i]; totS[i] = b; }
  }
  __syncthreads();
  {
    float offC = tid ? totC[tid - 1] : 0.f, offS = tid ? totS[tid - 1] : 0.f;
    int base = tid * (FB / 256);
    for (int k = 0; k < FB / 256; ++k) { sCnt[base + k] += offC; sPos[base + k] += offS; }
  }
  // replicate jnp: cdf = cumsum(hist); cdf = cdf/cdf[-1]*N  (f32)
  if (tid == 0) {
    float a = 0.f;
    for (int j = 0; j < NBINS; ++j) { a += th[(size_t)c * NBINS + j]; sCdf[j] = a; }
  }
  __syncthreads();
  float total = sCdf[NBINS - 1];
  int j = tid;
  float cs = (sCdf[j] / total) * (float)N_EL;
  int kj = (int)floorf(cs);
  kj = min(max(kj, 0), N_EL);
  float fk = (float)kj;
  float totCnt = sCnt[FB - 1];
  float totSumX = mn * totCnt + w * sPos[FB - 1];
  float S1;                                       // sum of the kj smallest x
  if (kj <= 0) S1 = 0.f;
  else if (fk >= totCnt) S1 = totSumX;
  else {
    int lo = 0, hi = FB - 1;
    while (lo < hi) { int mid = (lo + hi) >> 1; if (sCnt[mid] >= fk) hi = mid; else lo = mid + 1; }
    float cP = lo ? sCnt[lo - 1] : 0.f, pP = lo ? sPos[lo - 1] : 0.f;
    float cb = sCnt[lo] - cP, pb = sPos[lo] - pP;
    float Ppart = pP + (fk - cP) * (cb > 0.f ? pb / cb : 0.f);
    S1 = mn * fk + w * Ppart;
  }
  sS1[j] = S1; sK[j] = kj;
  __syncthreads();
  int kP = j ? sK[j - 1] : 0;
  float S1P = j ? sS1[j - 1] : 0.f;
  // last bin absorbs everything up to N exactly (clip in searchsorted)
  float kjEff = (j == NBINS - 1) ? (float)N_EL : (float)kj;
  float S1Eff = (j == NBINS - 1) ? totSumX : S1;
  float cj = kjEff - (float)kP;
  float dS1 = S1Eff - S1P;
  float tmn = tmn_p[c], tmx = tmx_p[c];
  float tj = ((float)j / 255.0f) * (tmx - tmn) + tmn;
  float part = cj * tj * tj - 2.0f * tj * dS1;
  for (int o = 32; o > 0; o >>= 1) part += __shfl_xor(part, o);
  if ((tid & 63) == 0) red[tid >> 6] = part;
  __syncthreads();
  if (tid == 0) {
    float Lc = red[0] + red[1] + red[2] + red[3] + sumx2[c];
    atomicAdd(&dout[0], Lc * (0.01f / ((float)C_CH * (float)N_EL)));
    dout[1 + C_CH * NBINS + c] = fdec(umin[c]);          // cur_min
    dout[1 + C_CH * NBINS + C_CH + c] = fdec(umax[c]);   // cur_max
  }
}

extern "C" void kernel_launch(void* const* d_in, const int* in_sizes, int n_in,
                              void* d_out, int out_size, void* d_ws, size_t ws_size,
                              hipStream_t stream) {
  const float* inp  = (const float*)d_in[0];
  const float* mask = (const float*)d_in[1];
  const float* th   = (const float*)d_in[2];
  const float* tmn  = (const float*)d_in[3];
  const float* tmx  = (const float*)d_in[4];
  float* out = (float*)d_out;

  unsigned* umin = (unsigned*)d_ws;
  unsigned* umax = umin + C_CH;
  float* sumx2   = (float*)(umax + C_CH);
  float* fineCnt = sumx2 + C_CH;
  float* fineFrac = fineCnt + (size_t)C_CH * FB;

  hipLaunchKernelGGL(k_init, dim3(1024), dim3(256), 0, stream,
                     umin, umax, sumx2, fineCnt, fineFrac, out);
  hipLaunchKernelGGL(k_minmax, dim3(C_CH * BPC_MM), dim3(256), 0, stream,
                     inp, mask, umin, umax);
  hipLaunchKernelGGL(k_hist, dim3(C_CH * BPC_H), dim3(512), 0, stream,
                     inp, mask, umin, umax, fineCnt, fineFrac, sumx2, out + 1);
  hipLaunchKernelGGL(k_fin, dim3(C_CH), dim3(256), 0, stream,
                     th, tmn, tmx, umin, umax, sumx2, fineCnt, fineFrac, out);
}

// Round 3
// 230.648 us; speedup vs baseline: 1.7836x; 1.1083x over previous
//
#include <hip/hip_runtime.h>

#define C_CH 128
#define N_EL 262144          // 512*512 per channel
#define NBINS 256
#define FB 4096              // fine bins used: 0..4080 (4080 = 16*255)
#define FBINS 4080.0f
#define BPC_MM 16            // blocks per channel, minmax pass
#define BPC_H 2              // blocks per channel, hist pass
typedef unsigned long long u64;

// padded LDS index: +1 float per 32 to break 32-way bank conflicts on tid*16 slices
#define PIDX(i) ((i) + ((i) >> 5))
#define FBP (FB + (FB >> 5))

// ---------------- pass A: per-block min/max partials (plain stores, no init needed)
__global__ __launch_bounds__(256) void k_minmax(const float* __restrict__ inp,
                                                const float* __restrict__ mask,
                                                float* __restrict__ pmn,
                                                float* __restrict__ pmx) {
  const int SEG = N_EL / BPC_MM;      // 16384 elements, 4096 float4
  int c = blockIdx.x / BPC_MM;
  int seg = blockIdx.x % BPC_MM;
  const float4* in4 = (const float4*)(inp + (size_t)c * N_EL + (size_t)seg * SEG);
  const float4* mk4 = (const float4*)(mask + (size_t)seg * SEG);
  float mn = INFINITY, mx = -INFINITY;
  int tid = threadIdx.x;
#pragma unroll
  for (int i = 0; i < 4; ++i) {
    float4 av[4], mv[4];
#pragma unroll
    for (int k = 0; k < 4; ++k) av[k] = in4[i * 1024 + k * 256 + tid];
#pragma unroll
    for (int k = 0; k < 4; ++k) mv[k] = mk4[i * 1024 + k * 256 + tid];
#pragma unroll
    for (int k = 0; k < 4; ++k) {
      float x0 = av[k].x * mv[k].x, x1 = av[k].y * mv[k].y;
      float x2 = av[k].z * mv[k].z, x3 = av[k].w * mv[k].w;
      mn = fminf(mn, fminf(fminf(x0, x1), fminf(x2, x3)));
      mx = fmaxf(mx, fmaxf(fmaxf(x0, x1), fmaxf(x2, x3)));
    }
  }
  for (int o = 32; o > 0; o >>= 1) { mn = fminf(mn, __shfl_xor(mn, o)); mx = fmaxf(mx, __shfl_xor(mx, o)); }
  __shared__ float smn[4], smx[4];
  if ((tid & 63) == 0) { smn[tid >> 6] = mn; smx[tid >> 6] = mx; }
  __syncthreads();
  if (tid == 0) {
    pmn[blockIdx.x] = fminf(fminf(smn[0], smn[1]), fminf(smn[2], smn[3]));
    pmx[blockIdx.x] = fmaxf(fmaxf(smx[0], smx[1]), fmaxf(smx[2], smx[3]));
  }
}

// ---------------- pass B: LDS fine hist (packed u64), plain-store flush to disjoint slices
__global__ __launch_bounds__(1024) void k_hist(const float* __restrict__ inp,
                                               const float* __restrict__ mask,
                                               const float* __restrict__ pmn,
                                               const float* __restrict__ pmx,
                                               u64* __restrict__ fineP,
                                               float* __restrict__ sx2p,
                                               float* __restrict__ dout) {
  __shared__ u64 lh[FB];              // 32 KB: (cnt<<46) | sum(frac * 2^28)
  __shared__ float sMnMx[2];
  const int SEG = N_EL / BPC_H;       // 131072 elements, 32768 float4
  int c = blockIdx.x / BPC_H, seg = blockIdx.x % BPC_H;
  int tid = threadIdx.x;
  for (int i = tid; i < FB; i += 1024) lh[i] = 0ull;
  if (tid == 0) {
    float m = INFINITY;
    for (int k = 0; k < BPC_MM; ++k) m = fminf(m, pmn[c * BPC_MM + k]);
    sMnMx[0] = m;
    if (blockIdx.x == 0) dout[0] = 0.f;   // loss accumulator for k_fin
  }
  if (tid == 64) {
    float M = -INFINITY;
    for (int k = 0; k < BPC_MM; ++k) M = fmaxf(M, pmx[c * BPC_MM + k]);
    sMnMx[1] = M;
  }
  __syncthreads();
  float mn = sMnMx[0], mx = sMnMx[1];
  float inv = FBINS / fmaxf(mx - mn, 1e-8f);
  const float4* in4 = (const float4*)(inp + (size_t)c * N_EL + (size_t)seg * SEG);
  const float4* mk4 = (const float4*)(mask + (size_t)seg * SEG);
  float sx2 = 0.f;
#pragma unroll
  for (int i = 0; i < 8; ++i) {
    float4 av[4], mv[4];
#pragma unroll
    for (int k = 0; k < 4; ++k) av[k] = in4[i * 4096 + k * 1024 + tid];
#pragma unroll
    for (int k = 0; k < 4; ++k) mv[k] = mk4[i * 4096 + k * 1024 + tid];
#pragma unroll
    for (int k = 0; k < 4; ++k) {
      float xs[4] = {av[k].x * mv[k].x, av[k].y * mv[k].y, av[k].z * mv[k].z, av[k].w * mv[k].w};
#pragma unroll
      for (int e = 0; e < 4; ++e) {
        float x = xs[e];
        sx2 += x * x;
        float vv = (x - mn) * inv;                 // position in fine-bin units
        vv = fminf(fmaxf(vv, 0.f), FBINS);         // [0, 4080]
        int fb = (int)vv;
        float frac = vv - (float)fb;               // [0,1)
        u64 pkt = (1ull << 46) | (u64)(frac * 268435456.0f);  // frac * 2^28
        atomicAdd(&lh[fb], pkt);
      }
    }
  }
  // block-reduce sum of squares
  for (int o = 32; o > 0; o >>= 1) sx2 += __shfl_xor(sx2, o);
  __shared__ float sw[16];
  if ((tid & 63) == 0) sw[tid >> 6] = sx2;
  __syncthreads();   // also orders all LDS atomics before flush
  if (tid == 0) {
    float t = 0.f;
    for (int k = 0; k < 16; ++k) t += sw[k];
    sx2p[blockIdx.x] = t;
  }
  // flush fine hist: plain u64 stores, disjoint per-block slice
  for (int i = tid; i < FB; i += 1024) fineP[(size_t)blockIdx.x * FB + i] = lh[i];
}

// inclusive block scan of (a,b) over 256 threads: wave shfl scan + wave-total combine
__device__ __forceinline__ void blockScan2(float& a, float& b, float* tA, float* tB, int tid) {
  int lane = tid & 63, wave = tid >> 6;
#pragma unroll
  for (int o = 1; o < 64; o <<= 1) {
    float na = __shfl_up(a, o), nb = __shfl_up(b, o);
    if (lane >= o) { a += na; b += nb; }
  }
  if (lane == 63) { tA[wave] = a; tB[wave] = b; }
  __syncthreads();
  float offA = 0.f, offB = 0.f;
  for (int wv = 0; wv < 3; ++wv)
    if (wv < wave) { offA += tA[wv]; offB += tB[wv]; }
  a += offA; b += offB;
  __syncthreads();
}

// ---------------- pass C: scans + searchsorted-equivalent + loss, parallel scans
__global__ __launch_bounds__(256) void k_fin(const float* __restrict__ th,
                                             const float* __restrict__ tmn_p,
                                             const float* __restrict__ tmx_p,
                                             const float* __restrict__ pmn,
                                             const float* __restrict__ pmx,
                                             const float* __restrict__ sx2p,
                                             const u64* __restrict__ fineP,
                                             float* __restrict__ dout) {
  __shared__ float sCnt[FBP], sPos[FBP];
  __shared__ float tA[4], tB[4];
  __shared__ float sCdf[NBINS];
  __shared__ float sS1[NBINS];
  __shared__ int sK[NBINS];
  __shared__ float red[4];
  __shared__ float sMnMx[2];
  int c = blockIdx.x, tid = threadIdx.x;
  if (tid == 0) {
    float m = INFINITY;
    for (int k = 0; k < BPC_MM; ++k) m = fminf(m, pmn[c * BPC_MM + k]);
    sMnMx[0] = m;
  }
  if (tid == 64) {
    float M = -INFINITY;
    for (int k = 0; k < BPC_MM; ++k) M = fmaxf(M, pmx[c * BPC_MM + k]);
    sMnMx[1] = M;
  }
  const u64 FMASK = (1ull << 46) - 1;
  for (int i = tid; i < FB; i += 256) {
    u64 p0 = fineP[(size_t)(c * BPC_H + 0) * FB + i];
    u64 p1 = fineP[(size_t)(c * BPC_H + 1) * FB + i];
    float cn = (float)(unsigned)((p0 >> 46) + (p1 >> 46));
    float fr = (float)((p0 & FMASK) + (p1 & FMASK)) * (1.0f / 268435456.0f);
    sCnt[PIDX(i)] = cn;
    sPos[PIDX(i)] = cn * (float)i + fr;           // sum of (fb+frac) in bin
  }
  __syncthreads();
  float mn = sMnMx[0], mx = sMnMx[1];
  float w = fmaxf(mx - mn, 1e-8f) / FBINS;        // fine-bin width
  // inclusive scan: 16-elem serial per thread, then parallel scan of thread totals
  float a = 0.f, b = 0.f;
  {
    int base = tid * (FB / 256);
    for (int k = 0; k < FB / 256; ++k) {
      a += sCnt[PIDX(base + k)]; sCnt[PIDX(base + k)] = a;
      b += sPos[PIDX(base + k)]; sPos[PIDX(base + k)] = b;
    }
  }
  float ta = a, tb = b;
  blockScan2(a, b, tA, tB, tid);                  // inclusive over thread totals
  {
    float offC = a - ta, offS = b - tb;           // exclusive prefix for this thread
    int base = tid * (FB / 256);
    for (int k = 0; k < FB / 256; ++k) { sCnt[PIDX(base + k)] += offC; sPos[PIDX(base + k)] += offS; }
  }
  __syncthreads();
  // target cdf: parallel scan of th row (jnp: cumsum then /total*N in f32)
  {
    float h = th[(size_t)c * NBINS + tid], dummy = 0.f;
    blockScan2(h, dummy, tA, tB, tid);
    sCdf[tid] = h;
  }
  __syncthreads();
  float total = sCdf[NBINS - 1];
  int j = tid;
  float cs = (sCdf[j] / total) * (float)N_EL;
  int kj = (int)floorf(cs);
  kj = min(max(kj, 0), N_EL);
  float fk = (float)kj;
  float totCnt = sCnt[PIDX(FB - 1)];
  float totSumX = mn * totCnt + w * sPos[PIDX(FB - 1)];
  float S1;                                       // sum of the kj smallest x
  if (kj <= 0) S1 = 0.f;
  else if (fk >= totCnt) S1 = totSumX;
  else {
    int lo = 0, hi = FB - 1;
    while (lo < hi) { int mid = (lo + hi) >> 1; if (sCnt[PIDX(mid)] >= fk) hi = mid; else lo = mid + 1; }
    float cP = lo ? sCnt[PIDX(lo - 1)] : 0.f, pP = lo ? sPos[PIDX(lo - 1)] : 0.f;
    float cb = sCnt[PIDX(lo)] - cP, pb = sPos[PIDX(lo)] - pP;
    float Ppart = pP + (fk - cP) * (cb > 0.f ? pb / cb : 0.f);
    S1 = mn * fk + w * Ppart;
  }
  sS1[j] = S1; sK[j] = kj;
  // coarse 256-bin hist from fine prefix sums (4080 = 16*255)
  float hj = sCnt[PIDX(16 * j + 15)] - (j ? sCnt[PIDX(16 * j - 1)] : 0.f);
  dout[1 + (size_t)c * NBINS + j] = hj;
  __syncthreads();
  int kP = j ? sK[j - 1] : 0;
  float S1P = j ? sS1[j - 1] : 0.f;
  // last bin absorbs everything up to N exactly (clip in searchsorted)
  float kjEff = (j == NBINS - 1) ? (float)N_EL : (float)kj;
  float S1Eff = (j == NBINS - 1) ? totSumX : S1;
  float cj = kjEff - (float)kP;
  float dS1 = S1Eff - S1P;
  float tmn = tmn_p[c], tmx = tmx_p[c];
  float tj = ((float)j / 255.0f) * (tmx - tmn) + tmn;
  float part = cj * tj * tj - 2.0f * tj * dS1;
  for (int o = 32; o > 0; o >>= 1) part += __shfl_xor(part, o);
  if ((tid & 63) == 0) red[tid >> 6] = part;
  __syncthreads();
  if (tid == 0) {
    float sx2 = sx2p[c * BPC_H] + sx2p[c * BPC_H + 1];
    float Lc = red[0] + red[1] + red[2] + red[3] + sx2;
    atomicAdd(&dout[0], Lc * (0.01f / ((float)C_CH * (float)N_EL)));
    dout[1 + C_CH * NBINS + c] = mn;              // cur_min
    dout[1 + C_CH * NBINS + C_CH + c] = mx;       // cur_max
  }
}

extern "C" void kernel_launch(void* const* d_in, const int* in_sizes, int n_in,
                              void* d_out, int out_size, void* d_ws, size_t ws_size,
                              hipStream_t stream) {
  const float* inp  = (const float*)d_in[0];
  const float* mask = (const float*)d_in[1];
  const float* th   = (const float*)d_in[2];
  const float* tmn  = (const float*)d_in[3];
  const float* tmx  = (const float*)d_in[4];
  float* out = (float*)d_out;

  u64* fineP   = (u64*)d_ws;                                  // 8B-aligned first
  float* pmn   = (float*)(fineP + (size_t)C_CH * BPC_H * FB);
  float* pmx   = pmn + C_CH * BPC_MM;
  float* sx2p  = pmx + C_CH * BPC_MM;

  hipLaunchKernelGGL(k_minmax, dim3(C_CH * BPC_MM), dim3(256), 0, stream,
                     inp, mask, pmn, pmx);
  hipLaunchKernelGGL(k_hist, dim3(C_CH * BPC_H), dim3(1024), 0, stream,
                     inp, mask, pmn, pmx, fineP, sx2p, out);
  hipLaunchKernelGGL(k_fin, dim3(C_CH), dim3(256), 0, stream,
                     th, tmn, tmx, pmn, pmx, sx2p, fineP, out);
}